// Round 1
// baseline (66.050 us; speedup 1.0000x reference)
//
#include <hip/hip_runtime.h>
#include <math.h>

#define NF 32
#define HH 1024
#define WW 1024

// Descend one level: node `idx` owns region (y0,x0,h,w); pick the child
// subregion containing pixel (py,px). Split dir = idx%2 (1 = vertical/cols),
// split at exact half (dims stay even: 1024 -> ... -> 32). Returns side.
__device__ __forceinline__ int descend(int idx, int py, int px,
                                       int& y0, int& x0, int& h, int& w) {
  int side;
  if (idx & 1) {            // vertical split: columns, side 0 = left
    int lw = w >> 1;
    if (px >= x0 + lw) { side = 1; x0 += lw; w -= lw; }
    else               { side = 0; w = lw; }
  } else {                  // horizontal split: rows, side 0 = top
    int th = h >> 1;
    if (py >= y0 + th) { side = 1; y0 += th; h -= th; }
    else               { side = 0; h = th; }
  }
  return side;
}

__global__ __launch_bounds__(256)
void fractal_kernel(const float* __restrict__ fc,
                    const float* __restrict__ fsel,
                    const int* __restrict__ temp,
                    float* __restrict__ out) {
  // Output is piecewise-constant on 32x32 tiles; one block per tile.
  __shared__ float sProbs[64][33];   // [idx*2+side][i], +1 pad: conflict-free
  __shared__ int   sOrder[64][3];    // top-3 indices per (idx, side)
  __shared__ float sSig[NF][3];      // sigmoid(frame_colors)
  __shared__ float sCol[3];          // final tile color

  const int tid  = threadIdx.x;
  const int tile = blockIdx.x;
  const int by = tile >> 5, bx = tile & 31;
  const int py = by * 32 + 16, px = bx * 32 + 16;  // tile interior point

  // temperature: python int scalar -> int32 array; hedge against float bits
  int   ti = temp[0];
  float t  = (ti > 0 && ti < 1000000) ? (float)ti : __int_as_float(ti);
  const float invT = 1.0f / t;

  // phase 1a: coalesced load of frame_selection (32x2x32 f32), scaled by 1/T
  for (int v = 0; v < 8; ++v) {
    int u = v * 256 + tid;
    sProbs[u >> 5][u & 31] = fsel[u] * invT;
  }
  if (tid >= 64 && tid < 160) {      // sigmoid of frame colors (wave 1/2)
    int j = tid - 64;
    sSig[j / 3][j % 3] = 1.0f / (1.0f + expf(-fc[j]));
  }
  __syncthreads();

  // phase 1b: wave 0, one lane per (idx,side) row: softmax + stable top-3
  if (tid < 64) {
    float m = -1e30f;
    for (int i = 0; i < 32; ++i) m = fmaxf(m, sProbs[tid][i]);
    float s = 0.f;
    for (int i = 0; i < 32; ++i) {
      float e = expf(sProbs[tid][i] - m);
      sProbs[tid][i] = e;
      s += e;
    }
    float inv = 1.0f / s;
    float v0 = -1.f, v1 = -1.f, v2 = -1.f;
    int   b0 = 0,    b1 = 0,    b2 = 0;
    for (int i = 0; i < 32; ++i) {
      float p = sProbs[tid][i] * inv;
      sProbs[tid][i] = p;
      // strict > scanning ascending i == np stable argsort(-p) tie behavior
      if (p > v0)      { v2=v1;b2=b1; v1=v0;b1=b0; v0=p;b0=i; }
      else if (p > v1) { v2=v1;b2=b1; v1=p;b1=i; }
      else if (p > v2) { v2=p;b2=i; }
    }
    sOrder[tid][0] = b0; sOrder[tid][1] = b1; sOrder[tid][2] = b2;
  }
  __syncthreads();

  // phase 2: wave 0 evaluates the 36 root-to-leaf paths (lane j = path j)
  // branching per depth: k = {3,3,2,2,1}
  if (tid < 64) {
    float c0 = 0.f, c1 = 0.f, c2 = 0.f;
    if (tid < 36) {
      int j = tid;
      int sel0 = j / 12; int r = j % 12;
      int sel1 = r / 4;  r &= 3;
      int sel2 = r >> 1;
      int sel3 = r & 1;
      int selArr[5] = { sel0, sel1, sel2, sel3, 0 };

      int idx = 0, ay = 0, ax = 0, ah = HH, aw = WW;
      float w = 1.0f;
      bool alive = true;
      for (int d = 0; d < 5; ++d) {
        int s   = descend(idx, py, px, ay, ax, ah, aw);
        int row = idx * 2 + s;
        int ci  = sOrder[row][selArr[d]];
        float p = sProbs[row][ci];
        if (p <= 1e-3f) { alive = false; break; }  // reference skip rule
        w  *= p;
        idx = ci;
      }
      if (alive) {
        c0 = w * sSig[idx][0];
        c1 = w * sSig[idx][1];
        c2 = w * sSig[idx][2];
      }
    }
    // 64-lane tree reduction (lanes 36..63 contribute 0)
    for (int off = 32; off > 0; off >>= 1) {
      c0 += __shfl_down(c0, off, 64);
      c1 += __shfl_down(c1, off, 64);
      c2 += __shfl_down(c2, off, 64);
    }
    if (tid == 0) { sCol[0] = c0; sCol[1] = c1; sCol[2] = c2; }
  }
  __syncthreads();

  // phase 3: broadcast-write the tile. out layout (3, 1024, 1024) C-order.
  // 256 threads x 3 channels x 1 float4 = 3072 floats = 32x32x3.
  const int r = tid >> 3;   // row in tile
  const int q = tid & 7;    // float4 slot in row (32 floats = 8 float4)
  for (int c = 0; c < 3; ++c) {
    float v = sCol[c];
    float4 val = make_float4(v, v, v, v);
    float* base = out + (size_t)c * (HH * WW)
                      + (size_t)(by * 32 + r) * WW + (size_t)bx * 32;
    ((float4*)base)[q] = val;
  }
}

extern "C" void kernel_launch(void* const* d_in, const int* in_sizes, int n_in,
                              void* d_out, int out_size, void* d_ws, size_t ws_size,
                              hipStream_t stream) {
  const float* fc   = (const float*)d_in[0];   // (32, 3) f32
  const float* fsel = (const float*)d_in[1];   // (32, 2, 32) f32
  const int*   temp = (const int*)d_in[2];     // scalar
  float* out = (float*)d_out;                  // (3, 1024, 1024) f32
  (void)in_sizes; (void)n_in; (void)out_size; (void)d_ws; (void)ws_size;
  fractal_kernel<<<dim3(1024), dim3(256), 0, stream>>>(fc, fsel, temp, out);
}